// Round 3
// baseline (5920.287 us; speedup 1.0000x reference)
//
#include <hip/hip_runtime.h>

// Delayed-feedback LSTM, persistent kernel: 256 WGs (1/CU), now 1024 threads.
// History: VGPR budget is pinned at 128/thread by the toolchain regardless of
// launch_bounds / flat_work_group_size / waves_per_eu (r0-r2: three variants,
// all 128). r2's pins+REGP22 overcommitted 176 regs into a 128 budget ->
// ~450 B/thread/step of scratch reloads (FETCH 2.4 GB, VALUBusy 34%).
// This round: claim the FULL 512 KB register file via 1024 threads x 128 VGPR
// (no attribute games). Serial h-matvec: 8 k-eighths (ke=tid>>7) x 8 gates
// (gl=tid&127), 16 pairs/gate split ZERO-SPILL by construction:
//   pairs 0..7  -> regs (wreg[8][8] = 64 u32, 256 KB chip-wide)
//   pairs 8..10 -> LDS, uint4-packed across gates (96 KB, all ds_read_b128)
//   pairs 11..15-> L2 stream (WgSA/WgSB prepack, 160 KB/step/CU, XCD-shared)
// h-history (hg) moves global->LDS (8 KB; old 63 KB LDS limit forced global);
// hh merges into it. LDS total 144 KB, 1 WG/CU. Bottleneck shifts to the L2
// weight stream (~2860 cyc/step); future levers: split tuning / fp8 stream.

#define BATCH   256
#define TSTEPS  1024
#define IN_DIM  64
#define HID     256
#define OUT_DIM 64
#define DELAY   20
#define CH      8
#define NCH     (TSTEPS / CH)
#define NTHR    1024

typedef unsigned int u32;
typedef _Float16 half2_t __attribute__((ext_vector_type(2)));

union H2U { u32 u; half2_t h; };
union H1U { unsigned short s; _Float16 h; };

__device__ __forceinline__ u32 pack2(float a, float b) {
    H2U x; x.h = half2_t{(_Float16)a, (_Float16)b}; return x.u;
}
__device__ __forceinline__ unsigned short f16bits(float a) {
    H1U x; x.h = (_Float16)a; return x.s;
}
__device__ __forceinline__ float lo16(u32 u) {
    H1U x; x.s = (unsigned short)(u & 0xffffu); return (float)x.h;
}
__device__ __forceinline__ float hi16(u32 u) {
    H1U x; x.s = (unsigned short)(u >> 16); return (float)x.h;
}
__device__ __forceinline__ float dot2(u32 w, u32 h, float acc) {
    H2U a; a.u = w; H2U b; b.u = h;
    return __builtin_amdgcn_fdot2(a.h, b.h, acc, false);
}
__device__ __forceinline__ float sigm(float x) {
    float e = __expf(-fabsf(x));
    float p = 1.f / (1.f + e);
    return x >= 0.f ? p : 1.f - p;
}
__device__ __forceinline__ float tanh_f(float x) {
    float e = __expf(-2.f * fabsf(x));
    float r = (1.f - e) / (1.f + e);
    return x >= 0.f ? r : -r;
}

// LDS layout (bytes), total 144000 <= 163840 (needs hipFuncSetAttribute)
#define OFF_LDSWA 0        // uint4[4 qq][1024 tid]  65536  W_hh pairs 8,9 (2 gates/ent)
#define OFF_LDSWB 65536    // uint4[2 qz][1024 tid]  32768  W_hh pair 10 (4 gates/ent)
#define OFF_CB    98304    // ushort[8 tl][1024 g]   16384  chunk gate pre-acts (f16)
#define OFF_PART  114688   // ushort[8 ke][1024 g]   16384  per-ke partials (f16)
#define OFF_RING  131072   // ushort[20][64]          2560  fb ring (f16)
#define OFF_XF    133632   // u32[8][68]              2176  staged x|fb pairs
#define OFF_HG    135808   // ushort[16][256]         8192  h history (f16)
#define SMEM_BYTES 144000

// ws layout (bytes)
#define WS_BPK   0         // 262144: chunk Wx|Wfb packed (uint4)
#define WS_WGSA  262144    // 131072: serial W_hh pairs 11..14 (uint4/gate)
#define WS_WGSB  393216    // 32768 : serial W_hh pair 15 (4 gates/uint4)
#define WS_WOUT  425984    // 32768 : packed Wout (u32)
#define WS_BSUM  458752    // 4096  : bias sums (float, permuted)
#define WS_NEED  462848

// permuted gate g' = u*4 + ty  ->  original row ty*256 + u  (ty: 0=i,1=f,2=g,3=o)
__device__ __forceinline__ int orig_row(int gp) {
    return (gp & 3) * 256 + (gp >> 2);
}

__global__ void prepack(const float* __restrict__ Wx,
                        const float* __restrict__ Wfb,
                        const float* __restrict__ Whh,
                        const float* __restrict__ Wout,
                        const float* __restrict__ bih,
                        const float* __restrict__ bhh,
                        uint4* __restrict__ Bpk4,
                        uint4* __restrict__ WgSA4,
                        uint4* __restrict__ WgSB4,
                        u32* __restrict__ Woutpk,
                        float* __restrict__ bsum_g)
{
    int id = blockIdx.x * 256 + threadIdx.x;
    if (id < 16384) {
        // Bpk4[(j*16+kb)*512 + t]: gate g'=2t+j, K=128 (x|fb), k = kb*8..kb*8+7
        int t = id & 511, rest = id >> 9;
        int kb = rest & 15, j = rest >> 4;
        int r = orig_row(2 * t + j);
        int k0 = kb * 8;
        const float* src = (k0 < 64) ? (Wx + (size_t)r * 64 + k0)
                                     : (Wfb + (size_t)r * 64 + (k0 - 64));
        uint4 v;
        v.x = pack2(src[0], src[1]); v.y = pack2(src[2], src[3]);
        v.z = pack2(src[4], src[5]); v.w = pack2(src[6], src[7]);
        Bpk4[id] = v;
    } else if (id < 24576) {
        // WgSA4[q*1024 + tid]: gate g'=(tid&127)*8+q, ke=tid>>7, k = ke*32+22..29
        int s = id - 16384;
        int t = s & 1023, q = s >> 10;
        int ke = t >> 7, gl = t & 127;
        int r = orig_row(gl * 8 + q);
        const float* w = Whh + (size_t)r * HID + ke * 32 + 22;
        uint4 v;
        v.x = pack2(w[0], w[1]); v.y = pack2(w[2], w[3]);
        v.z = pack2(w[4], w[5]); v.w = pack2(w[6], w[7]);
        WgSA4[s] = v;
    } else if (id < 26624) {
        // WgSB4[qz*1024 + tid]: pair 15 (k=ke*32+30,31) of gates gl*8+qz*4+j, j=0..3
        int s = id - 24576;
        int t = s & 1023, qz = s >> 10;
        int ke = t >> 7, gl = t & 127;
        u32 c[4];
#pragma unroll
        for (int j = 0; j < 4; ++j) {
            int r = orig_row(gl * 8 + qz * 4 + j);
            const float* w = Whh + (size_t)r * HID + ke * 32 + 30;
            c[j] = pack2(w[0], w[1]);
        }
        uint4 v; v.x = c[0]; v.y = c[1]; v.z = c[2]; v.w = c[3];
        WgSB4[s] = v;
    } else if (id < 34816) {
        int s = id - 26624;                 // (w4*64+o)*4+c
        int c = s & 3, o = (s >> 2) & 63, w4 = s >> 8;
        int kp = w4 * 4 + c;
        Woutpk[s] = pack2(Wout[o * HID + 2 * kp], Wout[o * HID + 2 * kp + 1]);
    } else if (id < 35840) {
        int g = id - 34816;
        int r = orig_row(g);
        bsum_g[g] = bih[r] + bhh[r];
    }
}

__global__ __attribute__((amdgpu_flat_work_group_size(NTHR, NTHR)))
void lstm_persist(const float* __restrict__ input,
                  const float* __restrict__ Whh,
                  const float* __restrict__ bout_g,
                  const uint4* __restrict__ Bpk4,
                  const uint4* __restrict__ WgSA4,
                  const uint4* __restrict__ WgSB4,
                  const u32* __restrict__ Woutpk,
                  const float* __restrict__ bsum_g,
                  float* __restrict__ out)
{
    extern __shared__ char smem[];
    uint4*          ldswA = (uint4*)(smem + OFF_LDSWA);
    uint4*          ldswB = (uint4*)(smem + OFF_LDSWB);
    unsigned short* cbh   = (unsigned short*)(smem + OFF_CB);
    unsigned short* part  = (unsigned short*)(smem + OFF_PART);
    unsigned short* ring  = (unsigned short*)(smem + OFF_RING);
    u32*            xfst  = (u32*)(smem + OFF_XF);
    unsigned short* hgs   = (unsigned short*)(smem + OFF_HG);

    const int tid = threadIdx.x;
    const int b   = blockIdx.x;
    const int ke  = tid >> 7;         // wave-uniform k-eighth
    const int gl  = tid & 127;        // gate block: permuted gates gl*8..gl*8+7

    const float* xin  = input + (size_t)b * TSTEPS * IN_DIM;
    float*       outp = out + (size_t)b * TSTEPS * OUT_DIM;
    const float bo_reg = bout_g[tid & 63];

    // ---- init: W_hh pairs 0..7 of k-eighth into regs, 8..10 into LDS ----
    u32 wreg[8][8];
#pragma unroll
    for (int q = 0; q < 8; ++q) {
        const int r = orig_row(gl * 8 + q);
        const float* wrow = Whh + (size_t)r * HID + ke * 32;
#pragma unroll
        for (int p = 0; p < 8; ++p) {
            float2 w2 = *(const float2*)(wrow + 2 * p);
            wreg[q][p] = pack2(w2.x, w2.y);
        }
    }
#pragma unroll
    for (int qq = 0; qq < 4; ++qq) {
        const int r0 = orig_row(gl * 8 + 2 * qq);
        const int r1 = orig_row(gl * 8 + 2 * qq + 1);
        const float* w0 = Whh + (size_t)r0 * HID + ke * 32 + 16;
        const float* w1 = Whh + (size_t)r1 * HID + ke * 32 + 16;
        uint4 v;
        v.x = pack2(w0[0], w0[1]); v.y = pack2(w0[2], w0[3]);
        v.z = pack2(w1[0], w1[1]); v.w = pack2(w1[2], w1[3]);
        ldswA[qq * 1024 + tid] = v;
    }
#pragma unroll
    for (int qz = 0; qz < 2; ++qz) {
        u32 c[4];
#pragma unroll
        for (int j = 0; j < 4; ++j) {
            const int r = orig_row(gl * 8 + qz * 4 + j);
            const float* w = Whh + (size_t)r * HID + ke * 32 + 20;
            c[j] = pack2(w[0], w[1]);
        }
        uint4 v; v.x = c[0]; v.y = c[1]; v.z = c[2]; v.w = c[3];
        ldswB[qz * 1024 + tid] = v;
    }
    // Anti-remat pins: keep wreg register-resident for the whole kernel.
#pragma unroll
    for (int q = 0; q < 8; ++q)
#pragma unroll
        for (int p = 0; p < 8; ++p)
            asm volatile("" : "+v"(wreg[q][p]));

    // zero h history (slot 15 = h_{-1} must be 0)
    {
        u32* hz = (u32*)hgs;
        hz[tid] = 0u; hz[1024 + tid] = 0u;
    }
    __syncthreads();

    float c_state = 0.f;

    // out matvec for steps [tbase, tbase+8): one (t,o) per thread, tid<512
    auto out_chunk = [&](int tbase) {
        if (tid < 512) {
            const int lt = tid >> 6, o = tid & 63;
            const int t = tbase + lt;
            const uint4* hrow = (const uint4*)(hgs + (t & 15) * HID);
            const uint4* wp = (const uint4*)Woutpk;
            float a = bo_reg;
            for (int w4 = 0; w4 < 32; ++w4) {
                uint4 wv = wp[w4 * 64 + o];
                uint4 hv = hrow[w4];
                a = dot2(wv.x, hv.x, a); a = dot2(wv.y, hv.y, a);
                a = dot2(wv.z, hv.z, a); a = dot2(wv.w, hv.w, a);
            }
            outp[(size_t)t * OUT_DIM + o] = a;
            ring[(t % DELAY) * 64 + o] = f16bits(a);
        }
    };

#pragma unroll 1
    for (int ch = 0; ch < NCH; ++ch) {
        const int t0 = ch * CH;
        if (ch > 0) out_chunk(t0 - CH);
        __syncthreads();

        // ---- stage x|fb rows (8 rows x 64 u32) as f16 pairs ----
        if (tid < 512) {
            int row = tid >> 6, p = tid & 63;
            int t = t0 + row;
            u32 v;
            if (p < 32) {
                float2 x2 = *(const float2*)(xin + (size_t)t * IN_DIM + 2 * p);
                v = pack2(x2.x, x2.y);
            } else {
                int src = t - DELAY;
                if (src >= 0) {
                    int d = 2 * (p - 32);
                    int sl = src % DELAY;
                    v = (u32)ring[sl * 64 + d] | ((u32)ring[sl * 64 + d + 1] << 16);
                } else v = 0u;
            }
            xfst[row * 68 + p] = v;
        }
        __syncthreads();

        // ---- chunk: cb[tl][g'] = bias + x@Wx^T + fb@Wfb^T (1 gate/thread) ----
        {
            float acc8[8];
#pragma unroll
            for (int i = 0; i < 8; ++i) acc8[i] = 0.f;
            const uint4* bA = Bpk4 + (tid & 1) * (16 * 512) + (tid >> 1);
#pragma unroll 1
            for (int kb = 0; kb < 16; ++kb) {
                uint4 w = bA[kb * 512];
#pragma unroll
                for (int tl = 0; tl < 8; ++tl) {
                    uint4 xv = *(const uint4*)(xfst + tl * 68 + kb * 4);
                    acc8[tl] = dot2(w.x, xv.x, acc8[tl]);
                    acc8[tl] = dot2(w.y, xv.y, acc8[tl]);
                    acc8[tl] = dot2(w.z, xv.z, acc8[tl]);
                    acc8[tl] = dot2(w.w, xv.w, acc8[tl]);
                }
            }
            float bs = bsum_g[tid];
#pragma unroll
            for (int tl = 0; tl < 8; ++tl)
                cbh[tl * 1024 + tid] = f16bits(acc8[tl] + bs);
        }
        __syncthreads();

        // ---- 8 serial steps ----
#pragma unroll 1
        for (int tl = 0; tl < CH; ++tl) {
            const int t = t0 + tl;
            const u32* hrow = (const u32*)hgs + ((t - 1) & 15) * 128 + ke * 16;

            // stream batch 1: gates 0..3 pairs 11..14 + pair-15 pack
            const uint4* wsa = WgSA4 + tid;
            uint4 sA0 = wsa[0];
            uint4 sA1 = wsa[1024];
            uint4 sA2 = wsa[2048];
            uint4 sA3 = wsa[3072];
            uint4 sB0 = WgSB4[tid];

            float acc[8];
            if (ke == 0) {
                uint4 cv = *(const uint4*)(cbh + tl * 1024 + gl * 8);
                acc[0] = lo16(cv.x); acc[1] = hi16(cv.x);
                acc[2] = lo16(cv.y); acc[3] = hi16(cv.y);
                acc[4] = lo16(cv.z); acc[5] = hi16(cv.z);
                acc[6] = lo16(cv.w); acc[7] = hi16(cv.w);
            } else {
#pragma unroll
                for (int q = 0; q < 8; ++q) acc[q] = 0.f;
            }

            uint4 h0 = *(const uint4*)(hrow + 0);
            uint4 h1 = *(const uint4*)(hrow + 4);
#pragma unroll
            for (int q = 0; q < 8; ++q) {
                acc[q] = dot2(wreg[q][0], h0.x, acc[q]);
                acc[q] = dot2(wreg[q][1], h0.y, acc[q]);
                acc[q] = dot2(wreg[q][2], h0.z, acc[q]);
                acc[q] = dot2(wreg[q][3], h0.w, acc[q]);
                acc[q] = dot2(wreg[q][4], h1.x, acc[q]);
                acc[q] = dot2(wreg[q][5], h1.y, acc[q]);
                acc[q] = dot2(wreg[q][6], h1.z, acc[q]);
                acc[q] = dot2(wreg[q][7], h1.w, acc[q]);
            }
            uint4 h2 = *(const uint4*)(hrow + 8);
            uint4 h3 = *(const uint4*)(hrow + 12);

            // consume batch 1 (gates 0..3)
            acc[0] = dot2(sA0.x, h2.w, acc[0]); acc[0] = dot2(sA0.y, h3.x, acc[0]);
            acc[0] = dot2(sA0.z, h3.y, acc[0]); acc[0] = dot2(sA0.w, h3.z, acc[0]);
            acc[1] = dot2(sA1.x, h2.w, acc[1]); acc[1] = dot2(sA1.y, h3.x, acc[1]);
            acc[1] = dot2(sA1.z, h3.y, acc[1]); acc[1] = dot2(sA1.w, h3.z, acc[1]);
            acc[2] = dot2(sA2.x, h2.w, acc[2]); acc[2] = dot2(sA2.y, h3.x, acc[2]);
            acc[2] = dot2(sA2.z, h3.y, acc[2]); acc[2] = dot2(sA2.w, h3.z, acc[2]);
            acc[3] = dot2(sA3.x, h2.w, acc[3]); acc[3] = dot2(sA3.y, h3.x, acc[3]);
            acc[3] = dot2(sA3.z, h3.y, acc[3]); acc[3] = dot2(sA3.w, h3.z, acc[3]);
            acc[0] = dot2(sB0.x, h3.w, acc[0]); acc[1] = dot2(sB0.y, h3.w, acc[1]);
            acc[2] = dot2(sB0.z, h3.w, acc[2]); acc[3] = dot2(sB0.w, h3.w, acc[3]);

            // stream batch 2: gates 4..7
            uint4 sA4 = wsa[4096];
            uint4 sA5 = wsa[5120];
            uint4 sA6 = wsa[6144];
            uint4 sA7 = wsa[7168];
            uint4 sB1 = WgSB4[1024 + tid];

            // LDS weights pairs 8,9 (la) and 10 (lb)
            uint4 la0 = ldswA[0 * 1024 + tid];
            uint4 la1 = ldswA[1 * 1024 + tid];
            uint4 la2 = ldswA[2 * 1024 + tid];
            uint4 la3 = ldswA[3 * 1024 + tid];
            uint4 lb0 = ldswB[tid];
            uint4 lb1 = ldswB[1024 + tid];
            acc[0] = dot2(la0.x, h2.x, acc[0]); acc[0] = dot2(la0.y, h2.y, acc[0]);
            acc[1] = dot2(la0.z, h2.x, acc[1]); acc[1] = dot2(la0.w, h2.y, acc[1]);
            acc[2] = dot2(la1.x, h2.x, acc[2]); acc[2] = dot2(la1.y, h2.y, acc[2]);
            acc[3] = dot2(la1.z, h2.x, acc[3]); acc[3] = dot2(la1.w, h2.y, acc[3]);
            acc[4] = dot2(la2.x, h2.x, acc[4]); acc[4] = dot2(la2.y, h2.y, acc[4]);
            acc[5] = dot2(la2.z, h2.x, acc[5]); acc[5] = dot2(la2.w, h2.y, acc[5]);
            acc[6] = dot2(la3.x, h2.x, acc[6]); acc[6] = dot2(la3.y, h2.y, acc[6]);
            acc[7] = dot2(la3.z, h2.x, acc[7]); acc[7] = dot2(la3.w, h2.y, acc[7]);
            acc[0] = dot2(lb0.x, h2.z, acc[0]); acc[1] = dot2(lb0.y, h2.z, acc[1]);
            acc[2] = dot2(lb0.z, h2.z, acc[2]); acc[3] = dot2(lb0.w, h2.z, acc[3]);
            acc[4] = dot2(lb1.x, h2.z, acc[4]); acc[5] = dot2(lb1.y, h2.z, acc[5]);
            acc[6] = dot2(lb1.z, h2.z, acc[6]); acc[7] = dot2(lb1.w, h2.z, acc[7]);

            // consume batch 2 (gates 4..7)
            acc[4] = dot2(sA4.x, h2.w, acc[4]); acc[4] = dot2(sA4.y, h3.x, acc[4]);
            acc[4] = dot2(sA4.z, h3.y, acc[4]); acc[4] = dot2(sA4.w, h3.z, acc[4]);
            acc[5] = dot2(sA5.x, h2.w, acc[5]); acc[5] = dot2(sA5.y, h3.x, acc[5]);
            acc[5] = dot2(sA5.z, h3.y, acc[5]); acc[5] = dot2(sA5.w, h3.z, acc[5]);
            acc[6] = dot2(sA6.x, h2.w, acc[6]); acc[6] = dot2(sA6.y, h3.x, acc[6]);
            acc[6] = dot2(sA6.z, h3.y, acc[6]); acc[6] = dot2(sA6.w, h3.z, acc[6]);
            acc[7] = dot2(sA7.x, h2.w, acc[7]); acc[7] = dot2(sA7.y, h3.x, acc[7]);
            acc[7] = dot2(sA7.z, h3.y, acc[7]); acc[7] = dot2(sA7.w, h3.z, acc[7]);
            acc[4] = dot2(sB1.x, h3.w, acc[4]); acc[5] = dot2(sB1.y, h3.w, acc[5]);
            acc[6] = dot2(sB1.z, h3.w, acc[6]); acc[7] = dot2(sB1.w, h3.w, acc[7]);

            {   // one ds_write_b128 of the 8-gate partial (f16)
                uint4 pw;
                pw.x = pack2(acc[0], acc[1]); pw.y = pack2(acc[2], acc[3]);
                pw.z = pack2(acc[4], acc[5]); pw.w = pack2(acc[6], acc[7]);
                *(uint4*)(part + ke * 1024 + gl * 8) = pw;
            }
            __syncthreads();

            if (tid < 256) {
                float s0 = 0.f, s1 = 0.f, s2 = 0.f, s3 = 0.f;
#pragma unroll
                for (int k8 = 0; k8 < 8; ++k8) {
                    uint2 rd = *(const uint2*)(part + k8 * 1024 + tid * 4);
                    s0 += lo16(rd.x); s1 += hi16(rd.x);
                    s2 += lo16(rd.y); s3 += hi16(rd.y);
                }
                // permuted order: ty 0=i, 1=f, 2=g, 3=o
                c_state = sigm(s1) * c_state + sigm(s0) * tanh_f(s2);
                float hval = sigm(s3) * tanh_f(c_state);
                hgs[(t & 15) * HID + tid] = f16bits(hval);
            }
            __syncthreads();
        }
    }
    out_chunk(TSTEPS - CH);
}

extern "C" void kernel_launch(void* const* d_in, const int* in_sizes, int n_in,
                              void* d_out, int out_size, void* d_ws, size_t ws_size,
                              hipStream_t stream)
{
    (void)in_sizes; (void)n_in; (void)out_size;
    const float* input = (const float*)d_in[0];
    const float* Wx    = (const float*)d_in[1];
    const float* Wfb   = (const float*)d_in[2];
    const float* Whh   = (const float*)d_in[3];
    const float* bih   = (const float*)d_in[4];
    const float* bhh   = (const float*)d_in[5];
    const float* Wo    = (const float*)d_in[6];
    const float* bog   = (const float*)d_in[7];
    float* out = (float*)d_out;

    if (ws_size < (size_t)WS_NEED) return;

    static bool attr_set = false;
    if (!attr_set) {
        hipFuncSetAttribute((const void*)lstm_persist,
                            hipFuncAttributeMaxDynamicSharedMemorySize,
                            SMEM_BYTES);
        attr_set = true;
    }

    uint4* Bpk4   = (uint4*)((char*)d_ws + WS_BPK);
    uint4* WgSA4  = (uint4*)((char*)d_ws + WS_WGSA);
    uint4* WgSB4  = (uint4*)((char*)d_ws + WS_WGSB);
    u32*   Woutpk = (u32*)((char*)d_ws + WS_WOUT);
    float* bsum_g = (float*)((char*)d_ws + WS_BSUM);

    prepack<<<dim3(140), dim3(256), 0, stream>>>(
        Wx, Wfb, Whh, Wo, bih, bhh, Bpk4, WgSA4, WgSB4, Woutpk, bsum_g);
    lstm_persist<<<dim3(BATCH), dim3(NTHR), SMEM_BYTES, stream>>>(
        input, Whh, bog, Bpk4, WgSA4, WgSB4, Woutpk, bsum_g, out);
}

// Round 4
// 5030.861 us; speedup vs baseline: 1.1768x; 1.1768x over previous
//
#include <hip/hip_runtime.h>

// Delayed-feedback LSTM, persistent kernel: 256 WGs (1/CU), 512 threads.
// ROOT CAUSE (r0-r3): all LDS was dynamic (extern __shared__), so the
// backend's occupancy model saw LDS=0 and budgeted VGPRs for max occupancy
// (512thr->128, 1024thr->64), rematerializing/spilling the W_hh register
// cache every round regardless of launch_bounds/waves_per_eu attributes.
// FIX: STATIC __shared__ smem[152192] -> compile-time-known 152 KB caps
// occupancy at 1 WG/CU = 2 waves/SIMD -> honest 256-VGPR budget, no
// occupancy incentive to remat. W_hh (512 KB f16) now fully on-chip:
//   pairs 0..24  -> wreg[8][25] = 200 VGPR/thread (400 KB chip-wide)
//   pairs 25..31 -> LDS 112 KB (uint4+uint2+u32 per gate, b128/b64/b32)
//   zero per-step global streaming in the serial loop.
// Serial h-matvec: kq=tid>>7 (k-quarter, 32 pairs), gl=tid&127 (8 gates).
// h-history lives in LDS (8 KB). Chunk phase (CH=8): x|fb gate matvec via
// dot2, Bpk streamed from L2 once per chunk (unchanged from r0).

#define BATCH   256
#define TSTEPS  1024
#define IN_DIM  64
#define HID     256
#define OUT_DIM 64
#define DELAY   20
#define CH      8
#define NCH     (TSTEPS / CH)
#define NTHR    512
#define REGP    25              // f16 pairs per gate in registers

typedef unsigned int u32;
typedef _Float16 half2_t __attribute__((ext_vector_type(2)));

union H2U { u32 u; half2_t h; };
union H1U { unsigned short s; _Float16 h; };

__device__ __forceinline__ u32 pack2(float a, float b) {
    H2U x; x.h = half2_t{(_Float16)a, (_Float16)b}; return x.u;
}
__device__ __forceinline__ unsigned short f16bits(float a) {
    H1U x; x.h = (_Float16)a; return x.s;
}
__device__ __forceinline__ float lo16(u32 u) {
    H1U x; x.s = (unsigned short)(u & 0xffffu); return (float)x.h;
}
__device__ __forceinline__ float hi16(u32 u) {
    H1U x; x.s = (unsigned short)(u >> 16); return (float)x.h;
}
__device__ __forceinline__ float dot2(u32 w, u32 h, float acc) {
    H2U a; a.u = w; H2U b; b.u = h;
    return __builtin_amdgcn_fdot2(a.h, b.h, acc, false);
}
__device__ __forceinline__ float sigm(float x) {
    float e = __expf(-fabsf(x));
    float p = 1.f / (1.f + e);
    return x >= 0.f ? p : 1.f - p;
}
__device__ __forceinline__ float tanh_f(float x) {
    float e = __expf(-2.f * fabsf(x));
    float r = (1.f - e) / (1.f + e);
    return x >= 0.f ? r : -r;
}

// STATIC LDS layout (bytes), total 152192 <= 163840
#define OFF_WA    0        // uint4[8 q][512 tid]   65536  W_hh pairs 25..28
#define OFF_WB    65536    // uint2[8 q][512 tid]   32768  W_hh pairs 29..30
#define OFF_WC    98304    // u32  [8 q][512 tid]   16384  W_hh pair 31
#define OFF_CB    114688   // u32  [8 tl][512]      16384  chunk pre-acts (2 gates/u32)
#define OFF_PART  131072   // ushort[4 kq][1024 g]   8192  per-kq partials (f16)
#define OFF_RING  139264   // ushort[20][64]         2560  fb ring (f16)
#define OFF_XF    141824   // u32[8][68]             2176  staged x|fb pairs
#define OFF_HG    144000   // ushort[16][256]        8192  h history (f16)
#define SMEM_BYTES 152192

// ws layout (bytes)
#define WS_BPK   0         // 262144: chunk Wx|Wfb packed (uint4)
#define WS_WOUT  262144    // 32768 : packed Wout (u32)
#define WS_BSUM  294912    // 4096  : bias sums (float, permuted)
#define WS_NEED  299008

// permuted gate g' = u*4 + ty  ->  original row ty*256 + u  (ty: 0=i,1=f,2=g,3=o)
__device__ __forceinline__ int orig_row(int gp) {
    return (gp & 3) * 256 + (gp >> 2);
}

__global__ void prepack(const float* __restrict__ Wx,
                        const float* __restrict__ Wfb,
                        const float* __restrict__ Whh,
                        const float* __restrict__ Wout,
                        const float* __restrict__ bih,
                        const float* __restrict__ bhh,
                        uint4* __restrict__ Bpk4,
                        u32* __restrict__ Woutpk,
                        float* __restrict__ bsum_g)
{
    (void)Whh;
    int id = blockIdx.x * 256 + threadIdx.x;
    if (id < 16384) {
        // Bpk4[(j*16+kb)*512 + t]: gate g'=2t+j, K=128 (x|fb), k = kb*8..kb*8+7
        int t = id & 511, rest = id >> 9;
        int kb = rest & 15, j = rest >> 4;
        int r = orig_row(2 * t + j);
        int k0 = kb * 8;
        const float* src = (k0 < 64) ? (Wx + (size_t)r * 64 + k0)
                                     : (Wfb + (size_t)r * 64 + (k0 - 64));
        uint4 v;
        v.x = pack2(src[0], src[1]); v.y = pack2(src[2], src[3]);
        v.z = pack2(src[4], src[5]); v.w = pack2(src[6], src[7]);
        Bpk4[id] = v;
    } else if (id < 16384 + 8192) {
        int s = id - 16384;                 // (w4*64+o)*4+c
        int c = s & 3, o = (s >> 2) & 63, w4 = s >> 8;
        int kp = w4 * 4 + c;
        Woutpk[s] = pack2(Wout[o * HID + 2 * kp], Wout[o * HID + 2 * kp + 1]);
    } else if (id < 16384 + 8192 + 1024) {
        int g = id - 24576;
        int r = orig_row(g);
        bsum_g[g] = bih[r] + bhh[r];
    }
}

__global__ __attribute__((amdgpu_flat_work_group_size(NTHR, NTHR)))
__attribute__((amdgpu_waves_per_eu(2, 2)))
void lstm_persist(const float* __restrict__ input,
                  const float* __restrict__ Whh,
                  const float* __restrict__ bout_g,
                  const uint4* __restrict__ Bpk4,
                  const u32* __restrict__ Woutpk,
                  const float* __restrict__ bsum_g,
                  float* __restrict__ out)
{
    __shared__ alignas(16) unsigned char smem[SMEM_BYTES];
    uint4*          wAl   = (uint4*)(smem + OFF_WA);
    uint2*          wBl   = (uint2*)(smem + OFF_WB);
    u32*            wCl   = (u32*)(smem + OFF_WC);
    u32*            cb32  = (u32*)(smem + OFF_CB);
    unsigned short* part  = (unsigned short*)(smem + OFF_PART);
    unsigned short* ring  = (unsigned short*)(smem + OFF_RING);
    u32*            xfst  = (u32*)(smem + OFF_XF);
    unsigned short* hgs   = (unsigned short*)(smem + OFF_HG);

    const int tid = threadIdx.x;
    const int b   = blockIdx.x;
    const int kq  = tid >> 7;         // wave-uniform k-quarter (32 pairs)
    const int gl  = tid & 127;        // gate block: permuted gates gl*8..gl*8+7

    const float* xin  = input + (size_t)b * TSTEPS * IN_DIM;
    float*       outp = out + (size_t)b * TSTEPS * OUT_DIM;
    const float bo_reg = bout_g[tid & 63];

    // ---- init: W_hh pairs 0..24 of k-quarter into regs, 25..31 into LDS ----
    u32 wreg[8][REGP];
#pragma unroll
    for (int q = 0; q < 8; ++q) {
        const int r = orig_row(gl * 8 + q);
        const float* wrow = Whh + (size_t)r * HID + kq * 64;
#pragma unroll
        for (int p = 0; p < REGP; ++p) {
            float2 w2 = *(const float2*)(wrow + 2 * p);
            wreg[q][p] = pack2(w2.x, w2.y);
        }
        uint4 av;
        av.x = pack2(wrow[50], wrow[51]); av.y = pack2(wrow[52], wrow[53]);
        av.z = pack2(wrow[54], wrow[55]); av.w = pack2(wrow[56], wrow[57]);
        wAl[q * 512 + tid] = av;
        uint2 bv;
        bv.x = pack2(wrow[58], wrow[59]); bv.y = pack2(wrow[60], wrow[61]);
        wBl[q * 512 + tid] = bv;
        wCl[q * 512 + tid] = pack2(wrow[62], wrow[63]);
    }
    // zero h history (slot 15 = h_{-1} must be 0; zero all for safety)
    {
        u32* hz = (u32*)hgs;
        hz[tid] = 0u; hz[512 + tid] = 0u; hz[1024 + tid] = 0u; hz[1536 + tid] = 0u;
    }
    __syncthreads();

    float c_state = 0.f;

    // out matvec for steps [tbase, tbase+8): one (t,o) per thread
    auto out_chunk = [&](int tbase) {
        const int lt = tid >> 6, o = tid & 63;
        const int t = tbase + lt;
        const uint4* hrow = (const uint4*)(hgs + (t & 15) * HID);
        const uint4* wp = (const uint4*)Woutpk;
        float a = bo_reg;
        for (int w4 = 0; w4 < 32; ++w4) {
            uint4 wv = wp[w4 * 64 + o];
            uint4 hv = hrow[w4];
            a = dot2(wv.x, hv.x, a); a = dot2(wv.y, hv.y, a);
            a = dot2(wv.z, hv.z, a); a = dot2(wv.w, hv.w, a);
        }
        outp[(size_t)t * OUT_DIM + o] = a;
        ring[(t % DELAY) * 64 + o] = f16bits(a);
    };

#pragma unroll 1
    for (int ch = 0; ch < NCH; ++ch) {
        // Anti-remat pins each chunk (zero-cost empty asm): keep wreg live in
        // VGPRs across the whole loop; allocator has a 256 budget (2 waves/EU
        // from the STATIC 152 KB LDS), so this fits without spill.
#pragma unroll
        for (int q = 0; q < 8; ++q)
#pragma unroll
            for (int p = 0; p < REGP; ++p)
                asm volatile("" : "+v"(wreg[q][p]));

        const int t0 = ch * CH;
        if (ch > 0) out_chunk(t0 - CH);
        __syncthreads();

        // ---- stage x|fb rows (8 rows x 64 u32) as f16 pairs ----
        {
            int row = tid >> 6, p = tid & 63;
            int t = t0 + row;
            u32 v;
            if (p < 32) {
                float2 x2 = *(const float2*)(xin + (size_t)t * IN_DIM + 2 * p);
                v = pack2(x2.x, x2.y);
            } else {
                int src = t - DELAY;
                if (src >= 0) {
                    int d = 2 * (p - 32);
                    int sl = src % DELAY;
                    v = (u32)ring[sl * 64 + d] | ((u32)ring[sl * 64 + d + 1] << 16);
                } else v = 0u;
            }
            xfst[row * 68 + p] = v;
        }
        __syncthreads();

        // ---- chunk: cb[tl][g'] = bias + x@Wx^T + fb@Wfb^T (dot2, 2 gates/thr)
        {
            float accA[8], accB[8];
#pragma unroll
            for (int i = 0; i < 8; ++i) { accA[i] = 0.f; accB[i] = 0.f; }
            const uint4* bA = Bpk4 + tid;
            const uint4* bB = Bpk4 + 16 * 512 + tid;
#pragma unroll 1
            for (int kb = 0; kb < 16; ++kb) {
                uint4 wA = bA[kb * 512];
                uint4 wB = bB[kb * 512];
#pragma unroll
                for (int tl = 0; tl < 8; ++tl) {
                    uint4 xv = *(const uint4*)(xfst + tl * 68 + kb * 4);
                    accA[tl] = dot2(wA.x, xv.x, accA[tl]);
                    accA[tl] = dot2(wA.y, xv.y, accA[tl]);
                    accA[tl] = dot2(wA.z, xv.z, accA[tl]);
                    accA[tl] = dot2(wA.w, xv.w, accA[tl]);
                    accB[tl] = dot2(wB.x, xv.x, accB[tl]);
                    accB[tl] = dot2(wB.y, xv.y, accB[tl]);
                    accB[tl] = dot2(wB.z, xv.z, accB[tl]);
                    accB[tl] = dot2(wB.w, xv.w, accB[tl]);
                }
            }
            float2 bs = *(const float2*)(bsum_g + 2 * tid);
#pragma unroll
            for (int tl = 0; tl < 8; ++tl)
                cb32[tl * 512 + tid] = pack2(accA[tl] + bs.x, accB[tl] + bs.y);
        }
        __syncthreads();

        // ---- 8 serial steps (k-halves: limits live h regs to 16) ----
#pragma unroll 1
        for (int tl = 0; tl < CH; ++tl) {
            const int t = t0 + tl;
            const u32* hrow = (const u32*)hgs + ((t - 1) & 15) * 128 + kq * 32;

            float acc[8];
            if (kq == 0) {
                uint4 cv = *(const uint4*)(cb32 + tl * 512 + gl * 4);
                acc[0] = lo16(cv.x); acc[1] = hi16(cv.x);
                acc[2] = lo16(cv.y); acc[3] = hi16(cv.y);
                acc[4] = lo16(cv.z); acc[5] = hi16(cv.z);
                acc[6] = lo16(cv.w); acc[7] = hi16(cv.w);
            } else {
#pragma unroll
                for (int q = 0; q < 8; ++q) acc[q] = 0.f;
            }
            {   // k-half 0: pairs 0..15 (all registers)
                uint4 h0 = *(const uint4*)(hrow + 0);
                uint4 h1 = *(const uint4*)(hrow + 4);
                uint4 h2 = *(const uint4*)(hrow + 8);
                uint4 h3 = *(const uint4*)(hrow + 12);
#pragma unroll
                for (int q = 0; q < 8; ++q) {
                    acc[q] = dot2(wreg[q][0],  h0.x, acc[q]);
                    acc[q] = dot2(wreg[q][1],  h0.y, acc[q]);
                    acc[q] = dot2(wreg[q][2],  h0.z, acc[q]);
                    acc[q] = dot2(wreg[q][3],  h0.w, acc[q]);
                    acc[q] = dot2(wreg[q][4],  h1.x, acc[q]);
                    acc[q] = dot2(wreg[q][5],  h1.y, acc[q]);
                    acc[q] = dot2(wreg[q][6],  h1.z, acc[q]);
                    acc[q] = dot2(wreg[q][7],  h1.w, acc[q]);
                    acc[q] = dot2(wreg[q][8],  h2.x, acc[q]);
                    acc[q] = dot2(wreg[q][9],  h2.y, acc[q]);
                    acc[q] = dot2(wreg[q][10], h2.z, acc[q]);
                    acc[q] = dot2(wreg[q][11], h2.w, acc[q]);
                    acc[q] = dot2(wreg[q][12], h3.x, acc[q]);
                    acc[q] = dot2(wreg[q][13], h3.y, acc[q]);
                    acc[q] = dot2(wreg[q][14], h3.z, acc[q]);
                    acc[q] = dot2(wreg[q][15], h3.w, acc[q]);
                }
            }
            {   // k-half 1: pairs 16..24 regs, 25..31 LDS
                uint4 h4 = *(const uint4*)(hrow + 16);
                uint4 h5 = *(const uint4*)(hrow + 20);
                uint4 h6 = *(const uint4*)(hrow + 24);
                uint4 h7 = *(const uint4*)(hrow + 28);
#pragma unroll
                for (int q = 0; q < 8; ++q) {
                    acc[q] = dot2(wreg[q][16], h4.x, acc[q]);
                    acc[q] = dot2(wreg[q][17], h4.y, acc[q]);
                    acc[q] = dot2(wreg[q][18], h4.z, acc[q]);
                    acc[q] = dot2(wreg[q][19], h4.w, acc[q]);
                    acc[q] = dot2(wreg[q][20], h5.x, acc[q]);
                    acc[q] = dot2(wreg[q][21], h5.y, acc[q]);
                    acc[q] = dot2(wreg[q][22], h5.z, acc[q]);
                    acc[q] = dot2(wreg[q][23], h5.w, acc[q]);
                    acc[q] = dot2(wreg[q][24], h6.x, acc[q]);
                    uint4 av = wAl[q * 512 + tid];
                    uint2 bv = wBl[q * 512 + tid];
                    u32   cv = wCl[q * 512 + tid];
                    acc[q] = dot2(av.x, h6.y, acc[q]);
                    acc[q] = dot2(av.y, h6.z, acc[q]);
                    acc[q] = dot2(av.z, h6.w, acc[q]);
                    acc[q] = dot2(av.w, h7.x, acc[q]);
                    acc[q] = dot2(bv.x, h7.y, acc[q]);
                    acc[q] = dot2(bv.y, h7.z, acc[q]);
                    acc[q] = dot2(cv,   h7.w, acc[q]);
                }
            }
            {   // one ds_write_b128 of the 8-gate partial (f16)
                uint4 pw;
                pw.x = pack2(acc[0], acc[1]); pw.y = pack2(acc[2], acc[3]);
                pw.z = pack2(acc[4], acc[5]); pw.w = pack2(acc[6], acc[7]);
                *(uint4*)(part + kq * 1024 + gl * 8) = pw;
            }
            __syncthreads();

            if (tid < 256) {
                float s0 = 0.f, s1 = 0.f, s2 = 0.f, s3 = 0.f;
#pragma unroll
                for (int k = 0; k < 4; ++k) {
                    uint2 rd = *(const uint2*)(part + k * 1024 + tid * 4);
                    s0 += lo16(rd.x); s1 += hi16(rd.x);
                    s2 += lo16(rd.y); s3 += hi16(rd.y);
                }
                // permuted order: ty 0=i, 1=f, 2=g, 3=o
                c_state = sigm(s1) * c_state + sigm(s0) * tanh_f(s2);
                float hval = sigm(s3) * tanh_f(c_state);
                hgs[(t & 15) * HID + tid] = f16bits(hval);
            }
            __syncthreads();
        }
    }
    out_chunk(TSTEPS - CH);
}

extern "C" void kernel_launch(void* const* d_in, const int* in_sizes, int n_in,
                              void* d_out, int out_size, void* d_ws, size_t ws_size,
                              hipStream_t stream)
{
    (void)in_sizes; (void)n_in; (void)out_size;
    const float* input = (const float*)d_in[0];
    const float* Wx    = (const float*)d_in[1];
    const float* Wfb   = (const float*)d_in[2];
    const float* Whh   = (const float*)d_in[3];
    const float* bih   = (const float*)d_in[4];
    const float* bhh   = (const float*)d_in[5];
    const float* Wo    = (const float*)d_in[6];
    const float* bog   = (const float*)d_in[7];
    float* out = (float*)d_out;

    if (ws_size < (size_t)WS_NEED) return;

    uint4* Bpk4   = (uint4*)((char*)d_ws + WS_BPK);
    u32*   Woutpk = (u32*)((char*)d_ws + WS_WOUT);
    float* bsum_g = (float*)((char*)d_ws + WS_BSUM);

    prepack<<<dim3(100), dim3(256), 0, stream>>>(
        Wx, Wfb, Whh, Wo, bih, bhh, Bpk4, Woutpk, bsum_g);
    lstm_persist<<<dim3(BATCH), dim3(NTHR), 0, stream>>>(
        input, Whh, bog, Bpk4, Woutpk, bsum_g, out);
}